// Round 3
// baseline (946.574 us; speedup 1.0000x reference)
//
#include <hip/hip_runtime.h>
#include <hip/hip_bf16.h>
#include <stdint.h>

// Problem constants (from reference): B=8,S=2048,IN=4096,OUT=4096,G=32
#define M_TOT 16384   // B*S
#define N_TOT 4096    // OUT
#define K_TOT 4096    // IN
#define NB    524288  // OUT*IN/G

// GEMM geometry: 256x256 tile, BK=64, 8 waves (2M x 4N). Round-3: fully
// pipelined reads (every operand >=1 phase ahead), 2 barriers/tile,
// persistent blocks (grid=256, 4 m-tiles per block at fixed n).
#define BM 256
#define BN 256
#define BK 64
#define NT (K_TOT / BK)   // 64 K-tiles
#define OT_PER_BLOCK 4

typedef __attribute__((ext_vector_type(8))) __bf16 bf16x8;
typedef __attribute__((ext_vector_type(4))) float f32x4;

#define BARF() do { asm volatile("" ::: "memory"); \
                    __builtin_amdgcn_s_barrier(); \
                    asm volatile("" ::: "memory"); } while (0)
#define VMW(n) asm volatile("s_waitcnt vmcnt(" #n ")" ::: "memory")

#define MFMA1(d, a, b) d = __builtin_amdgcn_mfma_f32_16x16x32_bf16(a, b, d, 0, 0, 0)
// 8 MFMA: one m-pair x 4 n-frags x one k-slice.
#define HALF(mb, A0k, A1k, Bk) do { \
  _Pragma("unroll") \
  for (int j_ = 0; j_ < 4; ++j_) { \
    MFMA1(acc[mb][j_],     A0k, Bk[j_]); \
    MFMA1(acc[(mb)+1][j_], A1k, Bk[j_]); \
  } \
} while (0)

// ---------------------------------------------------------------------------
// Kernel 1: dequantize int4-packed W -> bf16 [OUT, IN] row-major.
// Grid-stride (G11): 2048 blocks, each thread loops.
// ---------------------------------------------------------------------------
__global__ __launch_bounds__(256) void dequant_w(
    const int* __restrict__ packed,          // [NB, 16] int32, one byte each
    const float* __restrict__ scale,         // [NB] f32 (promoted from fp16)
    const int* __restrict__ mask,            // [NB] int32 (promoted from bool)
    __hip_bfloat16* __restrict__ wout)       // [OUT*IN] bf16
{
    const size_t total = (size_t)NB * 4;
    for (size_t t = (size_t)blockIdx.x * blockDim.x + threadIdx.x; t < total;
         t += (size_t)gridDim.x * blockDim.x) {
        const int4 pk = ((const int4*)packed)[t];
        size_t nb = t >> 2;
        float se = scale[nb] * (mask[nb] ? 1.0f : 0.5f);
        int vals[4] = { pk.x, pk.y, pk.z, pk.w };
        __hip_bfloat16 o[8];
#pragma unroll
        for (int j = 0; j < 4; ++j) {
            int v = vals[j];
            o[2*j]   = __float2bfloat16((float)((v & 0xF) - 8) * se);
            o[2*j+1] = __float2bfloat16((float)(((v >> 4) & 0xF) - 8) * se);
        }
        int4 st;
        __builtin_memcpy(&st, o, 16);
        ((int4*)wout)[t] = st;
    }
}

// ---------------------------------------------------------------------------
// Kernel 2: x fp32 -> bf16. Grid-stride (G11): 2048 blocks.
// ---------------------------------------------------------------------------
__global__ __launch_bounds__(256) void cvt_x(
    const float* __restrict__ x, __hip_bfloat16* __restrict__ xb)
{
    const size_t total = (size_t)M_TOT * K_TOT / 8;
    const float4* xp = (const float4*)x;
    for (size_t t = (size_t)blockIdx.x * blockDim.x + threadIdx.x; t < total;
         t += (size_t)gridDim.x * blockDim.x) {
        float4 a = xp[2*t], b = xp[2*t + 1];
        __hip_bfloat16 o[8] = {
            __float2bfloat16(a.x), __float2bfloat16(a.y),
            __float2bfloat16(a.z), __float2bfloat16(a.w),
            __float2bfloat16(b.x), __float2bfloat16(b.y),
            __float2bfloat16(b.z), __float2bfloat16(b.w)
        };
        int4 st;
        __builtin_memcpy(&st, o, 16);
        ((int4*)xb)[t] = st;
    }
}

// ---------------------------------------------------------------------------
// Kernel 3: C = A * W^T + bias.  Persistent: grid=256, block (xcd=bid&7,
// idx=bid>>3) owns nt = xcd*2+(idx&1), mt = (idx>>1)*4 + ot, ot=0..3.
// B panel (2MB) stays L2-resident across the 4 output tiles; A panels hit L3.
//
// Per-tile schedule (tile t, bufCur C=t&1, bufNxt N):  reads 12/4/4/4,
// MFMA 16/phase (k0-half then k1-half), 2 barriers + 1 vmcnt per tile.
//   p1: read a01(4) bK1(4) a23(4); MFMA m01 (k0 gated by a01 only — B k0
//       (BIN) prefetched last p4, bK1 gates the k1 half);  BARF
//   p2: read a45; stage A(t+1)->N.A (4), B(t+2)H0->C.B (2); MFMA m23
//   p3: read a67; stage B(t+2)H1->C.B (2); MFMA m45
//   p4: VMW(4); BARF; read BOUT = B(t+1) k0 from N.B (4); MFMA m67
// In-flight trace (steady, entry X = {B(t+1):4}):
//   p2 +6, p3 +2 -> 12; VMW(4) retires 8 oldest = B(t+1)+A(t+1) -> bufNxt
//   fully resident for p4's BOUT reads and next-p1's a/bK1 reads. ✓
// Stage-safety invariant (epoch = barrier-to-barrier): every staged region's
// last ds_reads are CONSUMED (hence drained) before the epoch-opening
// barrier: A(t+1)->N.A after a67(t-1) died at m67 (pre p1-trail);
// B(t+2)->C.B after bK0/bK1(t) died at p1's MFMAs (pre p1-trail). The
// p4->p1 boundary carries no stage, so it needs no barrier.
// Persistence: stage index t>=NT wraps t-=NT with next-ot A base (B base is
// fixed), so tiles 0',1' of the next output tile are staged by the tail of
// this one — the pipeline crosses output tiles with ZERO drain; the only
// per-ot serial cost is the C-store epilogue (stores don't touch LDS; the
// first VMW after it also drains them, which is conservative and safe).
// ---------------------------------------------------------------------------
__global__ __launch_bounds__(512, 2) void gemm_bt(
    const __hip_bfloat16* __restrict__ A,   // [M_TOT, K_TOT] bf16
    const __hip_bfloat16* __restrict__ Bw,  // [N_TOT, K_TOT] bf16
    const float* __restrict__ bias,         // [N_TOT]
    float* __restrict__ C)                  // [M_TOT, N_TOT]
{
    __shared__ __align__(16) char lds[131072];

    const int tid  = threadIdx.x;
    const int lane = tid & 63;
    const int wave = tid >> 6;
    const int wm = wave >> 2;   // 0..1 -> rows wm*128 of the 256-row tile
    const int wn = wave & 3;    // 0..3 -> cols wn*64

    const int xcd = blockIdx.x & 7;
    const int idx = blockIdx.x >> 3;        // 0..31
    const int nt  = xcd * 2 + (idx & 1);    // 0..15 (fixed per block)
    const int mg  = idx >> 1;               // 0..15; mt = mg*4 + ot
    const int n0  = nt * BN;

    // ---- staging addressing (per thread) ----
    // T2 swizzle: logical (row, byte-col cb) stored at cb ^ ((row&7)<<4).
    // global_load_lds dest is LINEAR; source col pre-swizzled (rule 21).
    const int srow = tid >> 3;                                   // 0..63
    const int scb  = ((tid & 7) * 16) ^ (((tid >> 3) & 7) << 4); // pre-swz src col
    const char* gB  = (const char*)Bw + ((size_t)(n0 + srow) * K_TOT) * 2 + scb;
    const char* gAc = (const char*)A  +
        ((size_t)(mg * 4 * BM + srow) * K_TOT) * 2 + scb;        // ot=0 base
    const char* gAn;                                             // wrap base
    char* lA = (char*)lds + tid * 16;            // + p*65536 + region*8192
    char* lB = (char*)lds + 32768 + tid * 16;

    auto stA = [&](int t) {                      // stage full A tile (4 loads)
        const char* g = gAc;
        if (t >= NT) { t -= NT; g = gAn; }       // wrap to next output tile
        const int p = t & 1;
        const size_t kb = (size_t)t * (BK * 2);
#pragma unroll
        for (int r = 0; r < 4; ++r) {
            __builtin_amdgcn_global_load_lds(
                (const __attribute__((address_space(1))) void*)
                    (g + kb + (size_t)r * 64 * K_TOT * 2),
                (__attribute__((address_space(3))) void*)
                    (lA + p * 65536 + r * 8192), 16, 0, 0);
        }
    };
    auto stB = [&](int t, int h) {               // stage B half-tile (2 loads)
        if (t >= NT) t -= NT;                    // B base fixed per block
        const int p = t & 1;
        const size_t kb = (size_t)t * (BK * 2);
#pragma unroll
        for (int s = 0; s < 2; ++s) {
            const int r = 2 * h + s;
            __builtin_amdgcn_global_load_lds(
                (const __attribute__((address_space(1))) void*)
                    (gB + kb + (size_t)r * 64 * K_TOT * 2),
                (__attribute__((address_space(3))) void*)
                    (lB + p * 65536 + r * 8192), 16, 0, 0);
        }
    };

    // ---- fragment read addressing ----
    // Fragment (16x16x32): lane l holds row (l&15), k = (l>>4)*8 + j.
    // phys byte col = (kk*64 + (l>>4)*16) ^ ((row&7)<<4); row&7 == lane&7.
    const int swz  = (lane & 7) << 4;
    const int pcb0 = (((lane >> 4) * 16) + 0)  ^ swz;   // k-slice 0
    const int pcb1 = (((lane >> 4) * 16) + 64) ^ swz;   // k-slice 1
    int arow[8], brow[4];
#pragma unroll
    for (int i = 0; i < 8; ++i) arow[i] = (wm * 128 + i * 16 + (lane & 15)) * 128;
#pragma unroll
    for (int j = 0; j < 4; ++j) brow[j] = (wn * 64 + j * 16 + (lane & 15)) * 128;

    f32x4 acc[8][4];

    const char* ldsA0 = (const char*)lds;
    const char* ldsB0 = (const char*)lds + 32768;
    const char* ldsA1 = (const char*)lds + 65536;
    const char* ldsB1 = (const char*)lds + 98304;

// One tile = 4 phases.  BIN = this tile's B k0 (prefetched), BOUT = next's.
#define TILE_BLOCK(Ap, Bp, BnB, BIN, BOUT, STG_A, STG_B0, STG_B1) do { \
    bf16x8 bK1[4], a01[2][2], a23[2][2]; \
    /* p1 */ \
    _Pragma("unroll") \
    for (int m_ = 0; m_ < 2; ++m_) { \
        a01[m_][0] = *(const bf16x8*)((Ap) + arow[m_] + pcb0); \
        a01[m_][1] = *(const bf16x8*)((Ap) + arow[m_] + pcb1); \
    } \
    _Pragma("unroll") \
    for (int j_ = 0; j_ < 4; ++j_) \
        bK1[j_] = *(const bf16x8*)((Bp) + brow[j_] + pcb1); \
    _Pragma("unroll") \
    for (int m_ = 0; m_ < 2; ++m_) { \
        a23[m_][0] = *(const bf16x8*)((Ap) + arow[2 + m_] + pcb0); \
        a23[m_][1] = *(const bf16x8*)((Ap) + arow[2 + m_] + pcb1); \
    } \
    __builtin_amdgcn_s_setprio(1); \
    HALF(0, a01[0][0], a01[1][0], BIN); \
    HALF(0, a01[0][1], a01[1][1], bK1); \
    __builtin_amdgcn_s_setprio(0); \
    BARF(); \
    { /* p2 */ \
        bf16x8 a45[2][2], a67[2][2]; \
        _Pragma("unroll") \
        for (int m_ = 0; m_ < 2; ++m_) { \
            a45[m_][0] = *(const bf16x8*)((Ap) + arow[4 + m_] + pcb0); \
            a45[m_][1] = *(const bf16x8*)((Ap) + arow[4 + m_] + pcb1); \
        } \
        STG_A; STG_B0; \
        __builtin_amdgcn_s_setprio(1); \
        HALF(2, a23[0][0], a23[1][0], BIN); \
        HALF(2, a23[0][1], a23[1][1], bK1); \
        __builtin_amdgcn_s_setprio(0); \
        /* p3 (no barrier: same epoch, invariant holds at epoch level) */ \
        _Pragma("unroll") \
        for (int m_ = 0; m_ < 2; ++m_) { \
            a67[m_][0] = *(const bf16x8*)((Ap) + arow[6 + m_] + pcb0); \
            a67[m_][1] = *(const bf16x8*)((Ap) + arow[6 + m_] + pcb1); \
        } \
        STG_B1; \
        __builtin_amdgcn_s_setprio(1); \
        HALF(4, a45[0][0], a45[1][0], BIN); \
        HALF(4, a45[0][1], a45[1][1], bK1); \
        __builtin_amdgcn_s_setprio(0); \
        /* p4 */ \
        VMW(4); \
        BARF(); \
        _Pragma("unroll") \
        for (int j_ = 0; j_ < 4; ++j_) \
            BOUT[j_] = *(const bf16x8*)((BnB) + brow[j_] + pcb0); \
        __builtin_amdgcn_s_setprio(1); \
        HALF(6, a67[0][0], a67[1][0], BIN); \
        HALF(6, a67[0][1], a67[1][1], bK1); \
        __builtin_amdgcn_s_setprio(0); \
    } \
} while (0)

    // Cold prologue: B(0) + A(0) + B(1) = 12 loads; VMW(4) retires
    // B(0)+A(0) (resident), leaves B(1):4 in flight (= steady-state X).
    bf16x8 bP[4], bQ[4];
    stB(0, 0); stB(0, 1); stA(0); stB(1, 0); stB(1, 1);
    VMW(4);
    BARF();
#pragma unroll
    for (int j = 0; j < 4; ++j)
        bP[j] = *(const bf16x8*)(ldsB0 + brow[j] + pcb0);   // B(0) k0

    const int cl = lane & 15;
    const int rq = (lane >> 4) * 4;

    for (int ot = 0; ot < OT_PER_BLOCK; ++ot) {
        gAn = (ot < OT_PER_BLOCK - 1)
                  ? gAc + (size_t)BM * K_TOT * 2   // next output tile's A
                  : gAc;                           // last ot: benign self-wrap
#pragma unroll
        for (int i = 0; i < 8; ++i)
#pragma unroll
            for (int j = 0; j < 4; ++j)
                acc[i][j] = (f32x4){0.f, 0.f, 0.f, 0.f};

        for (int it = 0; it < NT / 2; ++it) {
            const int ta = 2 * it, tb = ta + 1;
            TILE_BLOCK(ldsA0, ldsB0, ldsB1, bP, bQ,
                       stA(tb),     stB(ta + 2, 0), stB(ta + 2, 1));
            TILE_BLOCK(ldsA1, ldsB1, ldsB0, bQ, bP,
                       stA(tb + 1), stB(tb + 2, 0), stB(tb + 2, 1));
        }

        // Epilogue for this output tile. C/D layout col=lane&15,
        // row=(lane>>4)*4+reg (m89-verified). Stores don't touch LDS; the
        // in-flight wrapped stages for the next ot keep flowing underneath.
        const int m0 = (mg * 4 + ot) * BM;
#pragma unroll
        for (int j = 0; j < 4; ++j) {
            const int col = n0 + wn * 64 + j * 16 + cl;
            const float bv = bias[col];
#pragma unroll
            for (int i = 0; i < 8; ++i) {
                const size_t rbase = (size_t)(m0 + wm * 128 + i * 16 + rq);
#pragma unroll
                for (int r = 0; r < 4; ++r) {
                    C[(rbase + r) * N_TOT + col] = acc[i][j][r] + bv;
                }
            }
        }
        gAc = gAn;
    }
#undef TILE_BLOCK

    // Drain LDS-DMA (wrapped tail stages) before endpgm so a successor
    // block on this CU can't see a stray late write into its fresh LDS.
    VMW(0);
}

// ---------------------------------------------------------------------------
extern "C" void kernel_launch(void* const* d_in, const int* in_sizes, int n_in,
                              void* d_out, int out_size, void* d_ws, size_t ws_size,
                              hipStream_t stream) {
    const float* x      = (const float*)d_in[0];
    const int*   wp     = (const int*)d_in[1];
    const float* wscale = (const float*)d_in[2];   // fp16 promoted to f32 by harness
    const int*   wmask  = (const int*)d_in[3];     // bool promoted to int32
    const float* bias   = (const float*)d_in[4];
    float*       out    = (float*)d_out;

    // Workspace: W bf16 (32 MB) at offset 0, x bf16 (128 MB) after.
    __hip_bfloat16* Wb = (__hip_bfloat16*)d_ws;
    __hip_bfloat16* Xb = (__hip_bfloat16*)((char*)d_ws + (size_t)N_TOT * K_TOT * 2);

    // 1) dequant W (grid-stride, G11)
    dequant_w<<<2048, 256, 0, stream>>>(wp, wscale, wmask, Wb);
    // 2) convert x (grid-stride, G11)
    cvt_x<<<2048, 256, 0, stream>>>(x, Xb);
    // 3) GEMM: persistent, 256 blocks x 4 output tiles each
    gemm_bt<<<256, 512, 0, stream>>>(Xb, Wb, bias, out);
}

// Round 4
// 906.679 us; speedup vs baseline: 1.0440x; 1.0440x over previous
//
#include <hip/hip_runtime.h>
#include <hip/hip_bf16.h>
#include <stdint.h>

// Problem constants (from reference): B=8,S=2048,IN=4096,OUT=4096,G=32
#define M_TOT 16384   // B*S
#define N_TOT 4096    // OUT
#define K_TOT 4096    // IN
#define NB    524288  // OUT*IN/G

// GEMM geometry: 256x256 tile, BK=64, 8 waves (2M x 4N). Round-4 = round-2
// structure (best measured: 484us, MfmaUtil 51%) + k0-first MFMA ordering.
// Round-3's persistence + coarse 2-barrier merge regressed (530us, m196
// pattern: coarse phase-split hurts) and is reverted wholesale.
#define BM 256
#define BN 256
#define BK 64
#define NT (K_TOT / BK)   // 64 K-tiles

typedef __attribute__((ext_vector_type(8))) __bf16 bf16x8;
typedef __attribute__((ext_vector_type(4))) float f32x4;

#define BARF() do { asm volatile("" ::: "memory"); \
                    __builtin_amdgcn_s_barrier(); \
                    asm volatile("" ::: "memory"); } while (0)
#define VMW(n) asm volatile("s_waitcnt vmcnt(" #n ")" ::: "memory")

#define MFMA1(d, a, b) d = __builtin_amdgcn_mfma_f32_16x16x32_bf16(a, b, d, 0, 0, 0)
// 8 MFMA: one m-pair x 4 n-frags x ONE k-slice. k0-half issued before
// k1-half so the phase's first MFMA is gated by only the k0 operand reads
// (6 b128) instead of the full burst.
#define HALF(mb, A0k, A1k, Bk, ks) do { \
  _Pragma("unroll") \
  for (int j_ = 0; j_ < 4; ++j_) { \
    MFMA1(acc[mb][j_],     A0k, Bk[j_][ks]); \
    MFMA1(acc[(mb)+1][j_], A1k, Bk[j_][ks]); \
  } \
} while (0)

// ---------------------------------------------------------------------------
// Kernel 1: fused prep. Blocks [0,1024): dequant int4 W -> bf16 [OUT,IN].
// Blocks [1024,4096): cvt x f32 -> bf16. Both grid-stride, both BW-bound;
// fusing into one dispatch removes a launch and overlaps head/tail.
// ---------------------------------------------------------------------------
#define DQ_BLOCKS 1024
#define CV_BLOCKS 3072
__global__ __launch_bounds__(256) void prep(
    const int* __restrict__ packed,          // [NB, 16] int32, one byte each
    const float* __restrict__ scale,         // [NB] f32 (promoted from fp16)
    const int* __restrict__ mask,            // [NB] int32 (promoted from bool)
    __hip_bfloat16* __restrict__ wout,       // [OUT*IN] bf16
    const float* __restrict__ x,
    __hip_bfloat16* __restrict__ xb)
{
    if (blockIdx.x < DQ_BLOCKS) {
        const size_t total = (size_t)NB * 4;
        for (size_t t = (size_t)blockIdx.x * blockDim.x + threadIdx.x;
             t < total; t += (size_t)DQ_BLOCKS * 256) {
            const int4 pk = ((const int4*)packed)[t];
            size_t nb = t >> 2;
            float se = scale[nb] * (mask[nb] ? 1.0f : 0.5f);
            int vals[4] = { pk.x, pk.y, pk.z, pk.w };
            __hip_bfloat16 o[8];
#pragma unroll
            for (int j = 0; j < 4; ++j) {
                int v = vals[j];
                o[2*j]   = __float2bfloat16((float)((v & 0xF) - 8) * se);
                o[2*j+1] = __float2bfloat16((float)(((v >> 4) & 0xF) - 8) * se);
            }
            int4 st;
            __builtin_memcpy(&st, o, 16);
            ((int4*)wout)[t] = st;
        }
    } else {
        const size_t total = (size_t)M_TOT * K_TOT / 8;
        const float4* xp = (const float4*)x;
        for (size_t t = (size_t)(blockIdx.x - DQ_BLOCKS) * blockDim.x + threadIdx.x;
             t < total; t += (size_t)CV_BLOCKS * 256) {
            float4 a = xp[2*t], b = xp[2*t + 1];
            __hip_bfloat16 o[8] = {
                __float2bfloat16(a.x), __float2bfloat16(a.y),
                __float2bfloat16(a.z), __float2bfloat16(a.w),
                __float2bfloat16(b.x), __float2bfloat16(b.y),
                __float2bfloat16(b.z), __float2bfloat16(b.w)
            };
            int4 st;
            __builtin_memcpy(&st, o, 16);
            ((int4*)xb)[t] = st;
        }
    }
}

// ---------------------------------------------------------------------------
// Kernel 3: C[M,N] = A[M,K] * W[N,K]^T + bias.  256x256, 8 waves, BK=64.
//
// Round-2 schedule (restored): A-frag ds_reads pipelined one phase ahead;
// ONE barrier per phase (4/tile, 8/iter); stages p1:A(t+1), p2:B(t+2)H0,
// p3:B(t+2)H1; VMW(4) at p4 end.  Round-4 delta: within each phase, reads
// are issued k0-operands-first and MFMAs run k0-half then k1-half.
//
// In-flight trace (steady, entry X = {B(tile):4}):
//   p1 +4 (A(tile+1)) -> 8; p2 +2 -> 10; p3 +2 -> 12; p4 VMW(4) retires the
//   8 oldest = B(tile+1)+A(tile+1) -> other buffer fully resident for the
//   next tile-block's reads; leaves {B(tile+2):4} = next entry state.  ✓
// Stage-safety: every staged region's last ds_reads are consumed by an MFMA
//   before the barrier preceding the stage (A region's a67 dies at p4's
//   MFMA, staged next-p1; B region's reads die at p1's MFMAs, staged p2/p3).
// Tail: staged tile >= NT clamps t-=2 = tile already resident in that
//   buffer -> identical bytes, harmless.
// ---------------------------------------------------------------------------
__global__ __launch_bounds__(512, 2) void gemm_bt(
    const __hip_bfloat16* __restrict__ A,   // [M_TOT, K_TOT] bf16
    const __hip_bfloat16* __restrict__ Bw,  // [N_TOT, K_TOT] bf16
    const float* __restrict__ bias,         // [N_TOT]
    float* __restrict__ C)                  // [M_TOT, N_TOT]
{
    __shared__ __align__(16) char lds[131072];

    const int tid  = threadIdx.x;
    const int lane = tid & 63;
    const int wave = tid >> 6;
    const int wm = wave >> 2;   // 0..1 -> rows wm*128 of the 256-row tile
    const int wn = wave & 3;    // 0..3 -> cols wn*64

    // T1: bijective XCD swizzle (nwg=1024, 1024%8==0), m-fast within XCD:
    // each XCD owns nt pair {2x,2x+1} x all 64 mt -> B footprint 4MB ~ L2.
    const int wg = (blockIdx.x & 7) * 128 + (blockIdx.x >> 3);
    const int mt = wg & 63;
    const int nt = wg >> 6;
    const int m0 = mt * BM;
    const int n0 = nt * BN;

    // ---- staging addressing (per thread) ----
    // T2 swizzle: logical (row, byte-col cb) stored at cb ^ ((row&7)<<4).
    // global_load_lds dest is LINEAR; source col pre-swizzled (rule 21).
    const int srow = tid >> 3;                                   // 0..63
    const int scb  = ((tid & 7) * 16) ^ (((tid >> 3) & 7) << 4); // pre-swz src col
    const char* gA = (const char*)A  + ((size_t)(m0 + srow) * K_TOT) * 2 + scb;
    const char* gB = (const char*)Bw + ((size_t)(n0 + srow) * K_TOT) * 2 + scb;
    char* lA = (char*)lds + tid * 16;            // + p*65536 + region*8192
    char* lB = (char*)lds + 32768 + tid * 16;

    auto stA4 = [&](int t) {                     // stage full A tile (4 loads)
        if (t >= NT) t -= 2;                     // parity-preserving clamp
        const int p = t & 1;
        const size_t kb = (size_t)t * (BK * 2);
#pragma unroll
        for (int r = 0; r < 4; ++r) {
            __builtin_amdgcn_global_load_lds(
                (const __attribute__((address_space(1))) void*)
                    (gA + kb + (size_t)r * 64 * K_TOT * 2),
                (__attribute__((address_space(3))) void*)
                    (lA + p * 65536 + r * 8192), 16, 0, 0);
        }
    };
    auto stB2 = [&](int t, int h) {              // stage B half-tile (2 loads)
        if (t >= NT) t -= 2;
        const int p = t & 1;
        const size_t kb = (size_t)t * (BK * 2);
#pragma unroll
        for (int s = 0; s < 2; ++s) {
            const int r = 2 * h + s;
            __builtin_amdgcn_global_load_lds(
                (const __attribute__((address_space(1))) void*)
                    (gB + kb + (size_t)r * 64 * K_TOT * 2),
                (__attribute__((address_space(3))) void*)
                    (lB + p * 65536 + r * 8192), 16, 0, 0);
        }
    };

    // ---- fragment read addressing ----
    // Fragment (16x16x32): lane l holds row (l&15), k = (l>>4)*8 + j.
    // phys byte col = (kk*64 + (l>>4)*16) ^ ((row&7)<<4); row&7 == lane&7.
    const int swz  = (lane & 7) << 4;
    const int pcb0 = (((lane >> 4) * 16) + 0)  ^ swz;   // k-slice 0
    const int pcb1 = (((lane >> 4) * 16) + 64) ^ swz;   // k-slice 1
    int arow[8], brow[4];
#pragma unroll
    for (int i = 0; i < 8; ++i) arow[i] = (wm * 128 + i * 16 + (lane & 15)) * 128;
#pragma unroll
    for (int j = 0; j < 4; ++j) brow[j] = (wn * 64 + j * 16 + (lane & 15)) * 128;

    f32x4 acc[8][4] = {};

    const char* ldsA0 = (const char*)lds;
    const char* ldsB0 = (const char*)lds + 32768;
    const char* ldsA1 = (const char*)lds + 65536;
    const char* ldsB1 = (const char*)lds + 98304;

// One tile = 4 phases, 1 barrier each.  aCur/aNxt rotate (static idx, rule 20).
// Read issue order inside each phase: k0 operands first, then k1 — the
// phase's opening MFMA (k0-half) is gated by ~6 in-order ds_reads, not 12+.
#define TILE_BLOCK(Ap, Bp, STG_A, STG_B0, STG_B1) do { \
    bf16x8 bF[4][2], aCur[2][2], aNxt[2][2]; \
    /* p1: reads B + a01 + a23 (k0-first); stage A(t+1); MFMA m01 */ \
    _Pragma("unroll") \
    for (int j_ = 0; j_ < 4; ++j_) \
        bF[j_][0] = *(const bf16x8*)((Bp) + brow[j_] + pcb0); \
    _Pragma("unroll") \
    for (int m_ = 0; m_ < 2; ++m_) { \
        aCur[m_][0] = *(const bf16x8*)((Ap) + arow[m_] + pcb0); \
        aNxt[m_][0] = *(const bf16x8*)((Ap) + arow[2 + m_] + pcb0); \
    } \
    _Pragma("unroll") \
    for (int j_ = 0; j_ < 4; ++j_) \
        bF[j_][1] = *(const bf16x8*)((Bp) + brow[j_] + pcb1); \
    _Pragma("unroll") \
    for (int m_ = 0; m_ < 2; ++m_) { \
        aCur[m_][1] = *(const bf16x8*)((Ap) + arow[m_] + pcb1); \
        aNxt[m_][1] = *(const bf16x8*)((Ap) + arow[2 + m_] + pcb1); \
    } \
    STG_A; \
    __builtin_amdgcn_s_setprio(1); \
    HALF(0, aCur[0][0], aCur[1][0], bF, 0); \
    HALF(0, aCur[0][1], aCur[1][1], bF, 1); \
    __builtin_amdgcn_s_setprio(0); \
    BARF(); \
    /* p2: read a45 (ahead, k0-first); stage B(t+2)H0; MFMA m23 on aNxt */ \
    _Pragma("unroll") \
    for (int m_ = 0; m_ < 2; ++m_) \
        aCur[m_][0] = *(const bf16x8*)((Ap) + arow[4 + m_] + pcb0); \
    _Pragma("unroll") \
    for (int m_ = 0; m_ < 2; ++m_) \
        aCur[m_][1] = *(const bf16x8*)((Ap) + arow[4 + m_] + pcb1); \
    STG_B0; \
    __builtin_amdgcn_s_setprio(1); \
    HALF(2, aNxt[0][0], aNxt[1][0], bF, 0); \
    HALF(2, aNxt[0][1], aNxt[1][1], bF, 1); \
    __builtin_amdgcn_s_setprio(0); \
    BARF(); \
    /* p3: read a67 (ahead, k0-first); stage B(t+2)H1; MFMA m45 on aCur */ \
    _Pragma("unroll") \
    for (int m_ = 0; m_ < 2; ++m_) \
        aNxt[m_][0] = *(const bf16x8*)((Ap) + arow[6 + m_] + pcb0); \
    _Pragma("unroll") \
    for (int m_ = 0; m_ < 2; ++m_) \
        aNxt[m_][1] = *(const bf16x8*)((Ap) + arow[6 + m_] + pcb1); \
    STG_B1; \
    __builtin_amdgcn_s_setprio(1); \
    HALF(4, aCur[0][0], aCur[1][0], bF, 0); \
    HALF(4, aCur[0][1], aCur[1][1], bF, 1); \
    __builtin_amdgcn_s_setprio(0); \
    BARF(); \
    /* p4: no reads/stages; MFMA m67 on aNxt; counted vmcnt */ \
    __builtin_amdgcn_s_setprio(1); \
    HALF(6, aNxt[0][0], aNxt[1][0], bF, 0); \
    HALF(6, aNxt[0][1], aNxt[1][1], bF, 1); \
    __builtin_amdgcn_s_setprio(0); \
    VMW(4); \
    BARF(); \
} while (0)

    // Prologue: B(T0) + A(T0) + B(T1) = 12 loads; vmcnt(4) completes T0's
    // 8 (B+A resident), leaves B(T1)'s 4 in flight -> steady-state pattern.
    stB2(0, 0); stB2(0, 1); stA4(0); stB2(1, 0); stB2(1, 1);
    VMW(4);
    BARF();

    for (int it = 0; it < NT / 2; ++it) {
        const int ta = 2 * it, tb = ta + 1;
        TILE_BLOCK(ldsA0, ldsB0, stA4(tb),     stB2(ta + 2, 0), stB2(ta + 2, 1));
        TILE_BLOCK(ldsA1, ldsB1, stA4(ta + 2), stB2(tb + 2, 0), stB2(tb + 2, 1));
    }
#undef TILE_BLOCK

    // Epilogue: C/D layout col=lane&15, row=(lane>>4)*4+reg (m89-verified).
    const int cl = lane & 15;
    const int rq = (lane >> 4) * 4;
#pragma unroll
    for (int j = 0; j < 4; ++j) {
        const int col = n0 + wn * 64 + j * 16 + cl;
        const float bv = bias[col];
#pragma unroll
        for (int i = 0; i < 8; ++i) {
            const size_t rbase = (size_t)(m0 + wm * 128 + i * 16 + rq);
#pragma unroll
            for (int r = 0; r < 4; ++r) {
                C[(rbase + r) * N_TOT + col] = acc[i][j][r] + bv;
            }
        }
    }
    // Safety: drain LDS-DMA before endpgm so a successor block on this CU
    // can't see a stray late write into its freshly-allocated LDS.
    VMW(0);
}

// ---------------------------------------------------------------------------
extern "C" void kernel_launch(void* const* d_in, const int* in_sizes, int n_in,
                              void* d_out, int out_size, void* d_ws, size_t ws_size,
                              hipStream_t stream) {
    const float* x      = (const float*)d_in[0];
    const int*   wp     = (const int*)d_in[1];
    const float* wscale = (const float*)d_in[2];   // fp16 promoted to f32 by harness
    const int*   wmask  = (const int*)d_in[3];     // bool promoted to int32
    const float* bias   = (const float*)d_in[4];
    float*       out    = (float*)d_out;

    // Workspace: W bf16 (32 MB) at offset 0, x bf16 (128 MB) after.
    __hip_bfloat16* Wb = (__hip_bfloat16*)d_ws;
    __hip_bfloat16* Xb = (__hip_bfloat16*)((char*)d_ws + (size_t)N_TOT * K_TOT * 2);

    // 1) fused dequant W + convert x (one dispatch, both grid-stride)
    prep<<<DQ_BLOCKS + CV_BLOCKS, 256, 0, stream>>>(wp, wscale, wmask, Wb, x, Xb);
    // 2) GEMM: 64 x 16 tiles of 256x256, 512 threads (8 waves)
    gemm_bt<<<(M_TOT / BM) * (N_TOT / BN), 512, 0, stream>>>(Xb, Wb, bias, out);
}